// Round 4
// baseline (213.783 us; speedup 1.0000x reference)
//
#include <hip/hip_runtime.h>
#include <cmath>

constexpr int ISIZE = 512;
constexpr int REC   = 1024;
constexpr int NACT  = 18;
constexpr int BS    = 64;
constexpr float CLIPVAL = 2.0f;

constexpr int NSLOT = 16;  // 16 hebb i-chunk partials (x@W0^T folded into head)

// ws (floats): part 64*16*1024 = 1,048,576 + g 65,536 = 4.25 MB total.

typedef float f4 __attribute__((ext_vector_type(4)));

__device__ __forceinline__ f4 nt_load(const f4* p) {
#if __has_builtin(__builtin_nontemporal_load)
  return __builtin_nontemporal_load(p);
#else
  return *p;
#endif
}
__device__ __forceinline__ void nt_store(f4* p, f4 v) {
#if __has_builtin(__builtin_nontemporal_store)
  __builtin_nontemporal_store(v, p);
#else
  *p = v;
#endif
}

// ---------------------------------------------------------------------------
// Pass 1: EXACTLY 512 blocks = 2 full rounds on 256 CUs (no tail).
// Block = (ic, jh, bg): 64 i-rows x 512 j x 4 batches; thread: 4 j x 2 batches.
// bg fastest so 16 concurrent blocks share each w/alpha slice.
// Round 1 (ids 0..255) covers i 0..511; round 2 covers i 512..1023 — so the
// high-i half is L3-resident at pass-1 end, matching pass-2's descending-i
// read order.
__global__ __launch_bounds__(256) void k_pass1(
    const float* __restrict__ rv, const float* __restrict__ hebb,
    const float* __restrict__ w, const float* __restrict__ alpha,
    float* __restrict__ part) {
  const int id = blockIdx.x;
  const int t  = threadIdx.x;
  const int bg = id & 15;
  const int jh = (id >> 4) & 1;
  const int ic = id >> 5;              // 0..15
  const int b0 = bg * 4, i0 = ic * 64;
  const int jl = t & 127, bl = t >> 7;
  const int j0 = jh * 512 + jl * 4;
  const int ba = b0 + bl * 2;

  __shared__ float rvs[4][64];
  rvs[t >> 6][t & 63] = rv[(size_t)(b0 + (t >> 6)) * REC + i0 + (t & 63)];
  __syncthreads();

  f4 a0 = {0.f, 0.f, 0.f, 0.f}, a1 = {0.f, 0.f, 0.f, 0.f};
  const float* __restrict__ wp  = w     + (size_t)i0 * REC + j0;
  const float* __restrict__ ap  = alpha + (size_t)i0 * REC + j0;
  const float* __restrict__ hp0 = hebb + ((size_t)ba * REC + i0) * REC + j0;
  const float* __restrict__ hp1 = hp0 + (size_t)REC * REC;
  const float* __restrict__ r0s = &rvs[bl * 2][0];
  const float* __restrict__ r1s = &rvs[bl * 2 + 1][0];

#pragma unroll 4
  for (int ii = 0; ii < 64; ++ii) {
    const f4 wv = *(const f4*)(wp  + (size_t)ii * REC);
    const f4 av = *(const f4*)(ap  + (size_t)ii * REC);
    const f4 h0 = *(const f4*)(hp0 + (size_t)ii * REC);
    const f4 h1 = *(const f4*)(hp1 + (size_t)ii * REC);
    const float r0 = r0s[ii], r1 = r1s[ii];
    a0.x = fmaf(r0, fmaf(av.x, h0.x, wv.x), a0.x);
    a0.y = fmaf(r0, fmaf(av.y, h0.y, wv.y), a0.y);
    a0.z = fmaf(r0, fmaf(av.z, h0.z, wv.z), a0.z);
    a0.w = fmaf(r0, fmaf(av.w, h0.w, wv.w), a0.w);
    a1.x = fmaf(r1, fmaf(av.x, h1.x, wv.x), a1.x);
    a1.y = fmaf(r1, fmaf(av.y, h1.y, wv.y), a1.y);
    a1.z = fmaf(r1, fmaf(av.z, h1.z, wv.z), a1.z);
    a1.w = fmaf(r1, fmaf(av.w, h1.w, wv.w), a1.w);
  }
  *(f4*)(part + ((size_t)ba * NSLOT + ic) * REC + j0)       = a0;
  *(f4*)(part + ((size_t)(ba + 1) * NSLOT + ic) * REC + j0) = a1;
}

// ---------------------------------------------------------------------------
// Per-batch head, 1024 threads (t == j):
//  s = b0[j] + sum_16 partials + sum_k x[b,k]*W0[j,k]  -> h = tanh(s)
//  then logits (wave-per-action), myeta, softmax (t0), g.
__global__ __launch_bounds__(1024) void k_head(
    const float* __restrict__ part, const float* __restrict__ x,
    const float* __restrict__ W0, const float* __restrict__ b0,
    const float* __restrict__ W1, const float* __restrict__ b1,
    const float* __restrict__ h2w, const float* __restrict__ h2b,
    const float* __restrict__ mw, const float* __restrict__ mb,
    float* __restrict__ hact, float* __restrict__ act_dis,
    float* __restrict__ g) {
  const int b = blockIdx.x;
  const int t = threadIdx.x;  // == j
  __shared__ float xs[ISIZE];
  __shared__ float hsh[REC];
  __shared__ float logits_s[32];
  __shared__ float myeta_s;

  if (t < ISIZE) xs[t] = x[(size_t)b * ISIZE + t];
  __syncthreads();

  // x @ W0^T : thread j reads its own W0 row as f4 (line-efficient, L2/L3-hot)
  float xacc = 0.f;
  const f4* __restrict__ w0r = (const f4*)(W0 + (size_t)t * ISIZE);
#pragma unroll 8
  for (int kk = 0; kk < ISIZE / 4; ++kk) {
    const f4 wv = w0r[kk];
    const float* xk = &xs[kk * 4];
    xacc = fmaf(wv.x, xk[0], xacc);
    xacc = fmaf(wv.y, xk[1], xacc);
    xacc = fmaf(wv.z, xk[2], xacc);
    xacc = fmaf(wv.w, xk[3], xacc);
  }

  float s = b0[t] + xacc;
  const float* __restrict__ pb = part + (size_t)b * NSLOT * REC + t;
#pragma unroll
  for (int sl = 0; sl < NSLOT; ++sl) s += pb[(size_t)sl * REC];
  const float h = tanhf(s);
  hact[(size_t)b * REC + t] = h;
  hsh[t] = h;
  __syncthreads();

  const int wv = t >> 6, ln = t & 63;
  for (int a = wv; a < NACT; a += 16) {
    const float* __restrict__ w1a = W1 + (size_t)a * REC;
    float p = 0.f;
#pragma unroll
    for (int c = 0; c < 16; ++c) p = fmaf(hsh[c * 64 + ln], w1a[c * 64 + ln], p);
#pragma unroll
    for (int off = 32; off; off >>= 1) p += __shfl_down(p, off);
    if (ln == 0) logits_s[a] = p + b1[a];
  }
  if (wv == 0) {
    float p = 0.f;
#pragma unroll
    for (int c = 0; c < 16; ++c) p = fmaf(hsh[c * 64 + ln], h2w[c * 64 + ln], p);
#pragma unroll
    for (int off = 32; off; off >>= 1) p += __shfl_down(p, off);
    if (ln == 0) myeta_s = tanhf(p + h2b[0]);
  }
  __syncthreads();

  if (t == 0) {
    float m = logits_s[0];
    for (int a = 1; a < NACT; ++a) m = fmaxf(m, logits_s[a]);
    float e[NACT];
    float ssum = 0.f;
    for (int a = 0; a < NACT; ++a) { e[a] = expf(logits_s[a] - m); ssum += e[a]; }
    const float inv = 1.f / ssum;
    for (int a = 0; a < NACT; ++a) act_dis[(size_t)b * NACT + a] = e[a] * inv;
  }

  const float me = myeta_s;
  g[(size_t)b * REC + t] = fmaf(me, mw[t], mb[t]) * hsh[t];
}

// ---------------------------------------------------------------------------
// Pass 2: hebb_out = clip(hebb + rv[b,i]*g[b,j]); reverse of pass-1 read
// order (i desc slow, batch desc fast) to hit the L3-LRU-hot tail; nt hints
// keep pass-2 from polluting what it's about to read.
__global__ __launch_bounds__(256) void k_hebb(
    const float* __restrict__ hebb, const float* __restrict__ rv,
    const float* __restrict__ g, float* __restrict__ out) {
  const int b  = 63 - (int)blockIdx.x;
  const int i0 = (127 - (int)blockIdx.y) * 8;
  const int j0 = threadIdx.x * 4;
  const f4 gv = *(const f4*)(g + (size_t)b * REC + j0);
  const float* __restrict__ rvb = rv + (size_t)b * REC;
  const size_t base = ((size_t)b * REC + i0) * REC + j0;
#pragma unroll
  for (int ii = 0; ii < 8; ++ii) {
    const float r = rvb[i0 + ii];
    const f4 hv = nt_load((const f4*)(hebb + base + (size_t)ii * REC));
    f4 o;
    o.x = fminf(fmaxf(fmaf(r, gv.x, hv.x), -CLIPVAL), CLIPVAL);
    o.y = fminf(fmaxf(fmaf(r, gv.y, hv.y), -CLIPVAL), CLIPVAL);
    o.z = fminf(fmaxf(fmaf(r, gv.z, hv.z), -CLIPVAL), CLIPVAL);
    o.w = fminf(fmaxf(fmaf(r, gv.w, hv.w), -CLIPVAL), CLIPVAL);
    nt_store((f4*)(out + base + (size_t)ii * REC), o);
  }
}

// ---------------------------------------------------------------------------
extern "C" void kernel_launch(void* const* d_in, const int* in_sizes, int n_in,
                              void* d_out, int out_size, void* d_ws, size_t ws_size,
                              hipStream_t stream) {
  const float* x     = (const float*)d_in[0];
  const float* rv    = (const float*)d_in[1];
  const float* hebb  = (const float*)d_in[2];
  const float* w     = (const float*)d_in[3];
  const float* alpha = (const float*)d_in[4];
  const float* W0    = (const float*)d_in[5];
  const float* b0    = (const float*)d_in[6];
  const float* W1    = (const float*)d_in[7];
  const float* b1    = (const float*)d_in[8];
  const float* h2w   = (const float*)d_in[9];
  const float* h2b   = (const float*)d_in[10];
  const float* mw    = (const float*)d_in[11];
  const float* mb    = (const float*)d_in[12];

  float* out_act  = (float*)d_out;               // 64*18
  float* out_hact = out_act + (size_t)BS * NACT; // 64*1024
  float* out_hebb = out_hact + (size_t)BS * REC; // 64*1024*1024

  float* part = (float*)d_ws;                       // 64*16*1024
  float* g    = part + (size_t)BS * NSLOT * REC;    // 64*1024

  k_pass1<<<512, 256, 0, stream>>>(rv, hebb, w, alpha, part);
  k_head<<<BS, 1024, 0, stream>>>(part, x, W0, b0, W1, b1, h2w, h2b, mw, mb,
                                  out_hact, out_act, g);
  k_hebb<<<dim3(64, 128), 256, 0, stream>>>(hebb, rv, g, out_hebb);
}